// Round 15
// baseline (59.032 us; speedup 1.0000x reference)
//
#include <hip/hip_runtime.h>
#include <hip/hip_bf16.h>

typedef __attribute__((ext_vector_type(4))) float  f4;
typedef __attribute__((ext_vector_type(8))) short  short8;
typedef __attribute__((ext_vector_type(4))) float  f32x4;

static constexpr int NHEAD = 16;
static constexpr int NIN   = 128;
static constexpr int NOUT  = 128;
static constexpr int NROWS = 8 * 2048;          // B*S = 16384
static constexpr int RSTR  = NHEAD * NIN;       // 2048 floats (8KB) per (b,s) row
static constexpr int ROWS_PER_TILE  = 32;       // 16KB fp32 per tile
static constexpr int TILES          = 16;
static constexpr int ROWS_PER_BLOCK = ROWS_PER_TILE * TILES;   // 512
static constexpr int BLOCKS_X = NROWS / ROWS_PER_BLOCK;        // 32 -> 512 WGs = 2/CU

typedef __attribute__((address_space(3))) void  lds_void;
typedef const __attribute__((address_space(1))) void g_void;

static __device__ inline unsigned short f2bfu(float f) {
  union { __hip_bfloat16 h; unsigned short u; } v;
  v.h = __float2bfloat16(f);
  return v.u;
}

static __device__ inline short8 cvt8(f4 a, f4 b) {
  short8 r;
  r[0] = (short)f2bfu(a[0]); r[1] = (short)f2bfu(a[1]);
  r[2] = (short)f2bfu(a[2]); r[3] = (short)f2bfu(a[3]);
  r[4] = (short)f2bfu(b[0]); r[5] = (short)f2bfu(b[1]);
  r[6] = (short)f2bfu(b[2]); r[7] = (short)f2bfu(b[3]);
  return r;
}

__global__ __launch_bounds__(512, 4)   // 16 waves/CU target; VGPR cap 128 (need ~40)
void bdp_kernel(const float* __restrict__ X, const float* __restrict__ W,
                float* __restrict__ O) {
  // W(head) bf16 MFMA A-fragments, fragment-contiguous (conflict-floor reads):
  // frag = n*4 + kk; lane holds o = n*16 + (lane&15), k = kk*32 + (lane>>4)*8 + j.
  __shared__ short8 wtile[32][64];     // 32KB
  // X tile double buffer, fp32, LINEAR DMA image of 32 rows x 512B with the
  // source pre-swizzled so ds_read applies byte ^= (row&7)<<4 (rule #21:
  // linear dest + inverse-swizzled source + swizzle on read).
  __shared__ f4 xbuf[2][1024];         // 2 x 16KB

  const int head = blockIdx.y;
  const int tid  = (int)threadIdx.x;
  const int lane = tid & 63;
  const int wid  = tid >> 6;      // 8 waves
  const int lr   = lane & 15;
  const int lq   = lane >> 4;
  const int rg   = wid & 1;       // row group (16 rows) within 32-row tile
  const int nh   = wid >> 1;      // col pair: n in {2nh, 2nh+1}

  const int rowblock0 = (int)blockIdx.x * ROWS_PER_BLOCK;
  const char* Xh = (const char*)X + (size_t)head * NIN * 4;   // + row*8KB later

  // DMA one 16KB tile (2 rounds x 512 thr x 16B). LDS dest is wave-uniform
  // base + lane*16 (hardware); global source is per-lane, pre-swizzled.
#define STAGE(bi, t)                                                       \
  {                                                                        \
    const size_t rb = (size_t)(rowblock0 + (t) * ROWS_PER_TILE);           \
    _Pragma("unroll")                                                      \
    for (int r = 0; r < 2; ++r) {                                          \
      const int off = tid * 16 + r * 8192;      /* byte in tile image */   \
      const int row = off >> 9;                                            \
      const int wb  = off & 511;                                           \
      const int wbs = wb ^ ((row & 7) << 4);                               \
      const char* g = Xh + (rb + row) * (size_t)(RSTR * 4) + wbs;          \
      __builtin_amdgcn_global_load_lds(                                    \
          (g_void*)g,                                                      \
          (lds_void*)((char*)&xbuf[bi][0] + r * 8192 + wid * 1024),        \
          16, 0, 0);                                                       \
    }                                                                      \
  }

  // ---- prologue: tile 0 DMA in flight under W staging ----
  STAGE(0, 0)

  const float* Wh = W + (size_t)head * NOUT * NIN;
  #pragma unroll
  for (int it = 0; it < 4; ++it) {
    const int frag = wid * 4 + it;
    const int n  = frag >> 2;
    const int kk = frag & 3;
    const float* src = Wh + (n * 16 + lr) * NIN + kk * 32 + lq * 8;
    f4 a = *reinterpret_cast<const f4*>(src);
    f4 b = *reinterpret_cast<const f4*>(src + 4);
    wtile[frag][lane] = cvt8(a, b);
  }
  __syncthreads();   // vmcnt(0): W consumed AND tile-0 DMA landed

  for (int t = 0; t < TILES; ++t) {
    const int bi = t & 1;
    if (t + 1 < TILES) STAGE(bi ^ 1, t + 1)   // flies under compute+store

    // compute tile t from xbuf[bi]
    const char* xb = (const char*)&xbuf[bi][0];
    const int sw = (lr & 7) << 4;
    f32x4 acc0 = (f32x4){0.f, 0.f, 0.f, 0.f};
    f32x4 acc1 = (f32x4){0.f, 0.f, 0.f, 0.f};
    #pragma unroll
    for (int kk = 0; kk < 4; ++kk) {
      const int u0 = (rg * 16 + lr) * 512 + kk * 128 + lq * 32;
      f4 a = *reinterpret_cast<const f4*>(xb + (u0 ^ sw));
      f4 b = *reinterpret_cast<const f4*>(xb + ((u0 + 16) ^ sw));
      short8 xv = cvt8(a, b);
      acc0 = __builtin_amdgcn_mfma_f32_16x16x32_bf16(
          wtile[(nh * 2 + 0) * 4 + kk][lane], xv, acc0, 0, 0, 0);
      acc1 = __builtin_amdgcn_mfma_f32_16x16x32_bf16(
          wtile[(nh * 2 + 1) * 4 + kk][lane], xv, acc1, 0, 0, 0);
    }

    // D[o][xrow]: xrow = lane&15 (this wave's row rg*16+lr), o = n*16+lq*4+reg
    float* dst = O + (size_t)(rowblock0 + t * ROWS_PER_TILE + rg * 16 + lr) * RSTR
               + head * NOUT;
    *reinterpret_cast<f4*>(dst + (nh * 2 + 0) * 16 + lq * 4) = acc0;
    *reinterpret_cast<f4*>(dst + (nh * 2 + 1) * 16 + lq * 4) = acc1;

    __syncthreads();   // next-tile DMA drained; everyone done reading xbuf[bi]
  }
#undef STAGE
}

extern "C" void kernel_launch(void* const* d_in, const int* in_sizes, int n_in,
                              void* d_out, int out_size, void* d_ws, size_t ws_size,
                              hipStream_t stream) {
  const float* X = (const float*)d_in[0];   // [8,2048,16,128] f32
  const float* W = (const float*)d_in[1];   // [16,128,128] f32
  float* O = (float*)d_out;                 // [8,2048,16,128] f32
  dim3 grid(BLOCKS_X, NHEAD);
  bdp_kernel<<<grid, dim3(512), 0, stream>>>(X, W, O);
}